// Round 2
// baseline (229.554 us; speedup 1.0000x reference)
//
#include <hip/hip_runtime.h>
#include <hip/hip_bf16.h>

#define N_NODES 100000
#define N_PAD 100096         // 782 blocks * 128 rows
#define N_EDGES 600000
#define CH 128
#define N_GRAPHS 100
#define BN_EPS 1e-5f
#define NBUCKET 64
#define CAP 16               // per-node edge slab = exactly 1 cache line (64B)
#define OVFCAP 8192          // overflow list (deg>16: ~15 nodes for Poisson(6))
#define FILL_BLOCKS 586      // ceil(N_EDGES / (256*4))
#define GEMM_BLOCKS 782      // N_PAD / 128
#define GATHER_BLOCKS 1024
#define ZERO_INTS (N_NODES + 2 * NBUCKET * CH + 4)
#define ZERO_BLOCKS 455      // ceil(ZERO_INTS/256)

typedef __bf16 bf16x8 __attribute__((ext_vector_type(8)));
typedef float f32x4 __attribute__((ext_vector_type(4)));

__device__ __forceinline__ ushort f2bf(float f) {
    union { float f; unsigned u; } x; x.f = f;
    unsigned u = x.u;
    unsigned r = (u + 0x7fffu + ((u >> 16) & 1u)) >> 16;
    return (ushort)r;
}
__device__ __forceinline__ float bflo(unsigned p) { return __builtin_bit_cast(float, p << 16); }
__device__ __forceinline__ float bfhi(unsigned p) { return __builtin_bit_cast(float, p & 0xffff0000u); }

// ---------------------------------------------------------------------------
// k_prep: zero cnt/psum/psq/ovfcur + build Wt = bf16(W^T).
// Replaces hipMemsetAsync; Wt must exist before k_front's GEMM job.
// ---------------------------------------------------------------------------
__global__ __launch_bounds__(256) void k_prep(const float* __restrict__ W,
        int* __restrict__ zbase, ushort* __restrict__ Wt) {
    unsigned bid = blockIdx.x;
    if (bid < ZERO_BLOCKS) {
        int i = bid * 256 + threadIdx.x;
        if (i < ZERO_INTS) zbase[i] = 0;
    } else {
        int t = (bid - ZERO_BLOCKS) * 256 + threadIdx.x;  // 16384
        int k = t >> 7, o = t & 127;
        Wt[o * CH + k] = f2bf(W[t]);
    }
}

// ---------------------------------------------------------------------------
// A-fragment: 8 channels of bf16(h[row]*norm[row]) built in registers.
// ---------------------------------------------------------------------------
__device__ __forceinline__ bf16x8 mk_a(const float* __restrict__ hrow, int k,
                                       float nm, bool valid) {
    union { bf16x8 v; ushort u[8]; } r;
    if (valid) {
        float4 p = *(const float4*)(hrow + k);
        float4 q = *(const float4*)(hrow + k + 4);
        r.u[0] = f2bf(p.x * nm); r.u[1] = f2bf(p.y * nm);
        r.u[2] = f2bf(p.z * nm); r.u[3] = f2bf(p.w * nm);
        r.u[4] = f2bf(q.x * nm); r.u[5] = f2bf(q.y * nm);
        r.u[6] = f2bf(q.z * nm); r.u[7] = f2bf(q.w * nm);
    } else {
        #pragma unroll
        for (int i = 0; i < 8; i++) r.u[i] = 0;
    }
    return r.v;
}

// ---------------------------------------------------------------------------
// k_front: two concurrent jobs in one dispatch:
//   [0, FILL)   : fused count+fill — slot = atomicAdd(&cnt[dst],1),
//                 esrc[dst*CAP+slot] = src (overflow -> ovf list)
//   [FILL, ...) : z16 = bf16((h .* norm) @ W)  — GEMM moved BEFORE the
//                 aggregation (linearity: norm is a row scalar), so it no
//                 longer depends on the fill and runs under the atomic shadow.
// ---------------------------------------------------------------------------
__global__ __launch_bounds__(256) void k_front(const int* __restrict__ src,
        const int* __restrict__ dst, const float* __restrict__ h,
        const float* __restrict__ norm, const ushort* __restrict__ Wt,
        int* __restrict__ cnt, int* __restrict__ ovfcur, int* __restrict__ ovf,
        int* __restrict__ esrc, ushort* __restrict__ z16) {
    __shared__ ushort ys[128 * CH];   // 32 KB (GEMM staging; unused by fill blocks)
    unsigned bid = blockIdx.x;
    int tid = threadIdx.x;

    if (bid < FILL_BLOCKS) {
        int e0 = (bid * 256 + tid) * 4;
        if (e0 < N_EDGES) {                       // N_EDGES % 4 == 0
            int4 d = *(const int4*)(dst + e0);
            int4 s = *(const int4*)(src + e0);
            int s0 = atomicAdd(&cnt[d.x], 1);
            int s1 = atomicAdd(&cnt[d.y], 1);
            int s2 = atomicAdd(&cnt[d.z], 1);
            int s3 = atomicAdd(&cnt[d.w], 1);
            if (s0 < CAP) esrc[d.x * CAP + s0] = s.x;
            else { int p = atomicAdd(ovfcur, 1); if (p < OVFCAP) { ovf[2*p] = d.x; ovf[2*p+1] = s.x; } }
            if (s1 < CAP) esrc[d.y * CAP + s1] = s.y;
            else { int p = atomicAdd(ovfcur, 1); if (p < OVFCAP) { ovf[2*p] = d.y; ovf[2*p+1] = s.y; } }
            if (s2 < CAP) esrc[d.z * CAP + s2] = s.z;
            else { int p = atomicAdd(ovfcur, 1); if (p < OVFCAP) { ovf[2*p] = d.z; ovf[2*p+1] = s.z; } }
            if (s3 < CAP) esrc[d.w * CAP + s3] = s.w;
            else { int p = atomicAdd(ovfcur, 1); if (p < OVFCAP) { ovf[2*p] = d.w; ovf[2*p+1] = s.w; } }
        }
        return;
    }

    // ---- GEMM job: z[nb..nb+128) = bf16((h .* norm) @ W) ----
    int gb = bid - FILL_BLOCKS;
    int w = tid >> 6, L = tid & 63;
    int c15 = L & 15, quad = L >> 4;
    int nb = gb * 128 + w * 32;
    int r0 = nb + c15, r1 = nb + 16 + c15;
    bool v0r = r0 < N_NODES, v1r = r1 < N_NODES;
    float nm0 = v0r ? norm[r0] : 0.f;
    float nm1 = v1r ? norm[r1] : 0.f;
    const float* h0 = h + (size_t)r0 * CH;
    const float* h1 = h + (size_t)r1 * CH;

    f32x4 acc0[8] = {}, acc1[8] = {};
    #pragma unroll
    for (int kt = 0; kt < 4; kt++) {
        int k = kt * 32 + quad * 8;
        bf16x8 a0 = mk_a(h0, k, nm0, v0r);
        bf16x8 a1 = mk_a(h1, k, nm1, v1r);
        #pragma unroll
        for (int ot = 0; ot < 8; ot++) {
            bf16x8 b = *(const bf16x8*)(Wt + (size_t)(ot * 16 + c15) * CH + k);
            acc0[ot] = __builtin_amdgcn_mfma_f32_16x16x32_bf16(a0, b, acc0[ot], 0, 0, 0);
            acc1[ot] = __builtin_amdgcn_mfma_f32_16x16x32_bf16(a1, b, acc1[ot], 0, 0, 0);
        }
    }

    #pragma unroll
    for (int ot = 0; ot < 8; ot++) {
        int col = ot * 16 + c15;
        #pragma unroll
        for (int r = 0; r < 4; r++) {
            ys[(w * 32 + quad * 4 + r) * CH + col] = f2bf(acc0[ot][r]);
            ys[(w * 32 + 16 + quad * 4 + r) * CH + col] = f2bf(acc1[ot][r]);
        }
    }
    __syncthreads();
    {
        const uint4* ysv = (const uint4*)ys;
        uint4* out = (uint4*)(z16 + (size_t)gb * 128 * CH);
        #pragma unroll
        for (int i = 0; i < 8; i++) out[tid + i * 256] = ysv[tid + i * 256];
    }
}

// ---------------------------------------------------------------------------
// k_gather: grid-stride over nodes; 16 lanes/node, 8 ch/lane.
// agg = sum z16[src]; y = relu(agg*norm + bias); y16 store + BN stats.
// ---------------------------------------------------------------------------
__global__ __launch_bounds__(256) void k_gather(const ushort* __restrict__ z16,
        const float* __restrict__ norm, const int* __restrict__ cnt,
        const int* __restrict__ esrc, const int* __restrict__ ovfcur,
        const int* __restrict__ ovf, const float* __restrict__ bias,
        ushort* __restrict__ y16, float* __restrict__ psum, float* __restrict__ psq) {
    __shared__ float sred[2][16][CH];   // 16 KB

    int tid = threadIdx.x;
    int cg = tid & 15, rl = tid >> 4;
    int c = cg * 8;
    float4 b0 = *(const float4*)(bias + c), b1 = *(const float4*)(bias + c + 4);
    float s8[8] = {}, q8[8] = {};
    int no = min(*ovfcur, OVFCAP);

    for (int n = blockIdx.x * 16 + rl; n < N_NODES; n += GATHER_BLOCKS * 16) {
        int e = min(cnt[n], CAP);
        float nn = norm[n];
        int base = n * CAP;
        float a0=0.f,a1=0.f,a2=0.f,a3=0.f,a4=0.f,a5=0.f,a6=0.f,a7=0.f;
        int j = 0;
        for (; j + 4 <= e; j += 4) {
            int4 s4 = *(const int4*)(esrc + base + j);
            uint4 v0 = *(const uint4*)(z16 + (size_t)s4.x * CH + c);
            uint4 v1 = *(const uint4*)(z16 + (size_t)s4.y * CH + c);
            uint4 v2 = *(const uint4*)(z16 + (size_t)s4.z * CH + c);
            uint4 v3 = *(const uint4*)(z16 + (size_t)s4.w * CH + c);
            a0 += bflo(v0.x) + bflo(v1.x) + bflo(v2.x) + bflo(v3.x);
            a1 += bfhi(v0.x) + bfhi(v1.x) + bfhi(v2.x) + bfhi(v3.x);
            a2 += bflo(v0.y) + bflo(v1.y) + bflo(v2.y) + bflo(v3.y);
            a3 += bfhi(v0.y) + bfhi(v1.y) + bfhi(v2.y) + bfhi(v3.y);
            a4 += bflo(v0.z) + bflo(v1.z) + bflo(v2.z) + bflo(v3.z);
            a5 += bfhi(v0.z) + bfhi(v1.z) + bfhi(v2.z) + bfhi(v3.z);
            a6 += bflo(v0.w) + bflo(v1.w) + bflo(v2.w) + bflo(v3.w);
            a7 += bfhi(v0.w) + bfhi(v1.w) + bfhi(v2.w) + bfhi(v3.w);
        }
        for (; j < e; j++) {
            int s = esrc[base + j];
            uint4 v = *(const uint4*)(z16 + (size_t)s * CH + c);
            a0 += bflo(v.x); a1 += bfhi(v.x);
            a2 += bflo(v.y); a3 += bfhi(v.y);
            a4 += bflo(v.z); a5 += bfhi(v.z);
            a6 += bflo(v.w); a7 += bfhi(v.w);
        }
        if (no > 0) {
            for (int i = 0; i < no; i++) {
                if (ovf[2*i] == n) {
                    int s = ovf[2*i+1];
                    uint4 v = *(const uint4*)(z16 + (size_t)s * CH + c);
                    a0 += bflo(v.x); a1 += bfhi(v.x);
                    a2 += bflo(v.y); a3 += bfhi(v.y);
                    a4 += bflo(v.z); a5 += bfhi(v.z);
                    a6 += bflo(v.w); a7 += bfhi(v.w);
                }
            }
        }
        float f[8];
        f[0] = fmaxf(fmaf(a0, nn, b0.x), 0.f);
        f[1] = fmaxf(fmaf(a1, nn, b0.y), 0.f);
        f[2] = fmaxf(fmaf(a2, nn, b0.z), 0.f);
        f[3] = fmaxf(fmaf(a3, nn, b0.w), 0.f);
        f[4] = fmaxf(fmaf(a4, nn, b1.x), 0.f);
        f[5] = fmaxf(fmaf(a5, nn, b1.y), 0.f);
        f[6] = fmaxf(fmaf(a6, nn, b1.z), 0.f);
        f[7] = fmaxf(fmaf(a7, nn, b1.w), 0.f);
        uint4 o;
        o.x = (unsigned)f2bf(f[0]) | ((unsigned)f2bf(f[1]) << 16);
        o.y = (unsigned)f2bf(f[2]) | ((unsigned)f2bf(f[3]) << 16);
        o.z = (unsigned)f2bf(f[4]) | ((unsigned)f2bf(f[5]) << 16);
        o.w = (unsigned)f2bf(f[6]) | ((unsigned)f2bf(f[7]) << 16);
        *(uint4*)(y16 + (size_t)n * CH + c) = o;
        #pragma unroll
        for (int k = 0; k < 8; k++) { s8[k] += f[k]; q8[k] += f[k] * f[k]; }
    }

    // BN partial-stat flush: one atomic per column per block
    *(float4*)&sred[0][rl][c]     = make_float4(s8[0], s8[1], s8[2], s8[3]);
    *(float4*)&sred[0][rl][c + 4] = make_float4(s8[4], s8[5], s8[6], s8[7]);
    *(float4*)&sred[1][rl][c]     = make_float4(q8[0], q8[1], q8[2], q8[3]);
    *(float4*)&sred[1][rl][c + 4] = make_float4(q8[4], q8[5], q8[6], q8[7]);
    __syncthreads();
    if (tid < 128) {
        float S = 0.f, Q = 0.f;
        #pragma unroll
        for (int k = 0; k < 16; k++) { S += sred[0][k][tid]; Q += sred[1][k][tid]; }
        int bucket = blockIdx.x & (NBUCKET - 1);
        atomicAdd(&psum[bucket * CH + tid], S);
        atomicAdd(&psq[bucket * CH + tid], Q);
    }
}

// ---------------------------------------------------------------------------
__global__ void k_finalize(const float* __restrict__ psum, const float* __restrict__ psq,
        const float* __restrict__ gamma, const float* __restrict__ beta,
        float* __restrict__ scale, float* __restrict__ shift, float* __restrict__ phis) {
    int t = threadIdx.x;   // 128
    float S = 0.f, Q = 0.f;
    for (int g = 0; g < NBUCKET; g++) { S += psum[g * CH + t]; Q += psq[g * CH + t]; }
    const float invN = 1.f / (float)N_NODES;
    float mean = S * invN;
    float var  = Q * invN - mean * mean;
    float sc   = gamma[t] * rsqrtf(var + BN_EPS);
    scale[t] = sc;
    shift[t] = beta[t] - mean * sc;
    for (int i = t; i < N_GRAPHS * CH; i += 128) phis[i] = 0.f;
}

// ---------------------------------------------------------------------------
// BN apply (bf16 y16 -> f32 x) + per-graph pooling.
// ---------------------------------------------------------------------------
__global__ __launch_bounds__(256) void k_bnpool(const ushort* __restrict__ y16,
        const int* __restrict__ gids, const float* __restrict__ scale,
        const float* __restrict__ shift, float* __restrict__ xout,
        float* __restrict__ phis) {
    __shared__ float smP[16][CH];   // 8 KB

    int tid = threadIdx.x;
    int cg = tid & 15, rl = tid >> 4;
    int c = cg * 8;
    int r0 = blockIdx.x * 256;
    int rbase = r0 + rl * 16;

    float4 sc0 = *(const float4*)(scale + c), sc1 = *(const float4*)(scale + c + 4);
    float4 sh0 = *(const float4*)(shift + c), sh1 = *(const float4*)(shift + c + 4);

    bool fast = (r0 + 255 < N_NODES) && (gids[r0] == gids[r0 + 255]);

    if (fast) {
        float4 p0 = make_float4(0.f,0.f,0.f,0.f), p1 = make_float4(0.f,0.f,0.f,0.f);
        for (int j = 0; j < 16; j++) {
            int r = rbase + j;
            uint4 v = *(const uint4*)(y16 + (size_t)r * CH + c);
            float4 f0, f1;
            f0.x = fmaf(bflo(v.x), sc0.x, sh0.x); f0.y = fmaf(bfhi(v.x), sc0.y, sh0.y);
            f0.z = fmaf(bflo(v.y), sc0.z, sh0.z); f0.w = fmaf(bfhi(v.y), sc0.w, sh0.w);
            f1.x = fmaf(bflo(v.z), sc1.x, sh1.x); f1.y = fmaf(bfhi(v.z), sc1.y, sh1.y);
            f1.z = fmaf(bflo(v.w), sc1.z, sh1.z); f1.w = fmaf(bfhi(v.w), sc1.w, sh1.w);
            *(float4*)(xout + (size_t)r * CH + c) = f0;
            *(float4*)(xout + (size_t)r * CH + c + 4) = f1;
            p0.x += f0.x; p0.y += f0.y; p0.z += f0.z; p0.w += f0.w;
            p1.x += f1.x; p1.y += f1.y; p1.z += f1.z; p1.w += f1.w;
        }
        *(float4*)&smP[rl][c] = p0;
        *(float4*)&smP[rl][c + 4] = p1;
        __syncthreads();
        if (tid < 128) {
            int g = gids[r0];
            float S = 0.f;
            #pragma unroll
            for (int k = 0; k < 16; k++) S += smP[k][tid];
            atomicAdd(&phis[(size_t)g * CH + tid], S);
        }
    } else {
        float p[8] = {};
        int gprev = -1;
        for (int j = 0; j < 16; j++) {
            int r = rbase + j;
            if (r >= N_NODES) break;
            int g = gids[r];
            if (g != gprev) {
                if (gprev >= 0) {
                    #pragma unroll
                    for (int k = 0; k < 8; k++) {
                        atomicAdd(&phis[(size_t)gprev * CH + c + k], p[k]);
                        p[k] = 0.f;
                    }
                }
                gprev = g;
            }
            uint4 v = *(const uint4*)(y16 + (size_t)r * CH + c);
            float f[8];
            f[0] = fmaf(bflo(v.x), sc0.x, sh0.x); f[1] = fmaf(bfhi(v.x), sc0.y, sh0.y);
            f[2] = fmaf(bflo(v.y), sc0.z, sh0.z); f[3] = fmaf(bfhi(v.y), sc0.w, sh0.w);
            f[4] = fmaf(bflo(v.z), sc1.x, sh1.x); f[5] = fmaf(bfhi(v.z), sc1.y, sh1.y);
            f[6] = fmaf(bflo(v.w), sc1.z, sh1.z); f[7] = fmaf(bfhi(v.w), sc1.w, sh1.w);
            *(float4*)(xout + (size_t)r * CH + c) = make_float4(f[0], f[1], f[2], f[3]);
            *(float4*)(xout + (size_t)r * CH + c + 4) = make_float4(f[4], f[5], f[6], f[7]);
            #pragma unroll
            for (int k = 0; k < 8; k++) p[k] += f[k];
        }
        if (gprev >= 0) {
            #pragma unroll
            for (int k = 0; k < 8; k++)
                atomicAdd(&phis[(size_t)gprev * CH + c + k], p[k]);
        }
    }
}

// ---------------------------------------------------------------------------
extern "C" void kernel_launch(void* const* d_in, const int* in_sizes, int n_in,
                              void* d_out, int out_size, void* d_ws, size_t ws_size,
                              hipStream_t stream)
{
    const float* h     = (const float*)d_in[0];
    const float* norm  = (const float*)d_in[1];
    const float* W     = (const float*)d_in[2];
    const float* b     = (const float*)d_in[3];
    const float* gamma = (const float*)d_in[4];
    const float* beta  = (const float*)d_in[5];
    const int*   src   = (const int*)d_in[6];
    const int*   dst   = (const int*)d_in[7];
    const int*   gids  = (const int*)d_in[8];

    float* x_out = (float*)d_out;                       // [N,128]
    float* phis  = x_out + (size_t)N_NODES * CH;        // [100,128]

    ushort* z16  = (ushort*)d_ws;                       // [N_PAD,128] bf16 (h.*norm)@W
    ushort* y16  = z16 + (size_t)N_PAD * CH;            // [N_PAD,128] bf16 relu(...)
    ushort* Wt   = y16 + (size_t)N_PAD * CH;            // [128,128] bf16 W^T
    // ---- zeroed region (k_prep) ----
    int*   cnt     = (int*)(Wt + CH * CH);              // [N] per-node edge count
    float* psum    = (float*)(cnt + N_NODES);           // [64,128]
    float* psq     = psum + NBUCKET * CH;               // [64,128]
    int*   ovfcur  = (int*)(psq + NBUCKET * CH);        // [4]
    // ---- end zeroed region ----
    int*   esrc    = ovfcur + 4;                        // [N*CAP] slabs (1 line/node)
    int*   ovf     = esrc + (size_t)N_NODES * CAP;      // [2*OVFCAP] (dst,src) pairs
    float* scale   = (float*)(ovf + 2 * OVFCAP);        // [128]
    float* shift   = scale + CH;                        // [128]

    k_prep<<<ZERO_BLOCKS + 64, 256, 0, stream>>>(W, cnt, Wt);
    k_front<<<FILL_BLOCKS + GEMM_BLOCKS, 256, 0, stream>>>(
        src, dst, h, norm, Wt, cnt, ovfcur, ovf, esrc, z16);
    k_gather<<<GATHER_BLOCKS, 256, 0, stream>>>(
        z16, norm, cnt, esrc, ovfcur, ovf, b, y16, psum, psq);
    k_finalize<<<1, 128, 0, stream>>>(psum, psq, gamma, beta, scale, shift, phis);
    k_bnpool<<<(N_NODES + 255) / 256, 256, 0, stream>>>(y16, gids, scale, shift, x_out, phis);
}